// Round 11
// baseline (86.851 us; speedup 1.0000x reference)
//
#include <hip/hip_runtime.h>

// OurButterflyLayer: N=4096, LOGN=12, IN=1024, OUT=4096, BATCH=8192
//
// out[s,j] = scale[j] * z_s[src[j]],  z_s = 10-stage butterfly (stages 0..9)
// on the 1024-float input row s; stages 10,11 + out-row gather fold into
// per-output (scale, src) pairs (elements >=1024 stay zero through stages
// 0..9 since all strides < 1024).
//
// Round-11: split-pair pipeline. 512 blocks x 256 thr, 4 samples/wave:
//   bf(x0,x1) -> emit(0,1) -> bf(x2,x3) -> emit(2,3)
// Pair-0's stores retire (L2->HBM) during pair-1's butterfly, so the HBM
// write stream is active over ~2x the window (R10 bunched all stores at the
// tail -> additive compute+store phases). Butterfly/emit bodies are R10's
// verified code. Plain loads/stores (R7 fix). Stage-5..9 coeffs in 40 KB
// swizzled LDS (persistent; separate 32 KB z-scratch, LDS 72 KB -> 2 blk/CU).

typedef float f4 __attribute__((ext_vector_type(4)));
typedef float f2 __attribute__((ext_vector_type(2)));
typedef int   i4 __attribute__((ext_vector_type(4)));

__device__ __forceinline__ int swz(int e) {
    // XOR float-index bits [6:5] into [3:2]: keeps float4 alignment; makes
    // 64B-stride LDS coeff accesses bank-conflict-free.
    return e ^ (((e >> 5) & 3) << 2);
}

template<int CTRL>
__device__ __forceinline__ float dppx(float x) {
    int xi = __builtin_bit_cast(int, x);
    int r  = __builtin_amdgcn_update_dpp(xi, xi, CTRL, 0xF, 0xF, true);
    return __builtin_bit_cast(float, r);
}
// ctrl: quad_perm(1,0,3,2)=0xB1 (lane^1), quad_perm(2,3,0,1)=0x4E (lane^2),
// row_ror:8=0x128 (lane^8 within 16-lane row). All verified R4/R6/R7/R8/R10.

__global__ void __launch_bounds__(256) bfly_prep(
    const float* __restrict__ lp, const int* __restrict__ orow,
    float* __restrict__ scale, int* __restrict__ src2)
{
    int j = blockIdx.x * 256 + threadIdx.x;
    if (j >= 4096) return;
    int r = orow[j];
    int c = r & 1023;
    int u = r & 2047;
    const float* A10 = lp + 20 * 4096;
    const float* B10 = lp + 21 * 4096;
    const float* A11 = lp + 22 * 4096;
    const float* B11 = lp + 23 * 4096;
    float f11 = (r & 2048) ? B11[u] : A11[u];
    float f10 = (r & 1024) ? B10[c] : A10[c];
    scale[j] = f11 * f10;
    // f2-slot index with pair-preserving bank spread:
    // pz(c) = c ^ (((c>>4)&7)<<1)   (matches z-write slot algebra below)
    src2[j] = c ^ (((c >> 4) & 7) << 1);
}

__global__ void __launch_bounds__(256, 2) bfly_main(
    const float* __restrict__ inp, const float* __restrict__ lp,
    const float* __restrict__ scale, const int* __restrict__ src2,
    float* __restrict__ out)
{
    __shared__ __align__(16) float cf[10 * 1024];   // stages 5..9 coeffs, persistent
    __shared__ __align__(16) float zb[4 * 2048];    // per-wave paired-z scratch
    const int t = threadIdx.x;
    const int wave = t >> 6, lane = t & 63;

    // cooperative coeff staging: lp rows 10..19, first 1024 floats of each
    #pragma unroll
    for (int q = 0; q < 10; ++q) {
        const f4 v = *reinterpret_cast<const f4*>(lp + (size_t)(10 + q) * 4096 + t * 4);
        *reinterpret_cast<f4*>(&cf[q * 1024 + swz(t * 4)]) = v;
    }

    const int sBase = blockIdx.x * 16 + wave * 4;   // 4 samples per wave
    float xA[2][16], xB[2][16];
    #pragma unroll
    for (int m = 0; m < 2; ++m) {
        const f4* p = reinterpret_cast<const f4*>(inp + (size_t)(sBase + m) * 1024 + lane * 16);
        #pragma unroll
        for (int c = 0; c < 4; ++c) {
            f4 v = p[c];
            xA[m][4*c+0] = v.x; xA[m][4*c+1] = v.y; xA[m][4*c+2] = v.z; xA[m][4*c+3] = v.w;
        }
    }
    #pragma unroll
    for (int m = 0; m < 2; ++m) {
        const f4* p = reinterpret_cast<const f4*>(inp + (size_t)(sBase + 2 + m) * 1024 + lane * 16);
        #pragma unroll
        for (int c = 0; c < 4; ++c) {
            f4 v = p[c];
            xB[m][4*c+0] = v.x; xB[m][4*c+1] = v.y; xB[m][4*c+2] = v.z; xB[m][4*c+3] = v.w;
        }
    }

    __syncthreads();   // cf ready

    auto butterfly = [&](float (&x)[2][16]) {
        // ---- stages 0,1 (s=1,2): pairs within each f4 quarter ----
        #pragma unroll
        for (int i = 0; i < 2; ++i) {
            const f4* A = reinterpret_cast<const f4*>(lp + (size_t)(2*i)   * 4096 + lane * 16);
            const f4* B = reinterpret_cast<const f4*>(lp + (size_t)(2*i+1) * 4096 + lane * 16);
            #pragma unroll
            for (int c = 0; c < 4; ++c) {
                f4 va = A[c], vb = B[c];
                #pragma unroll
                for (int m = 0; m < 2; ++m) {
                    float* xm = x[m];
                    if (i == 0) {          // pairs (0,1),(2,3)
                        float lo0 = xm[4*c+0], hi0 = xm[4*c+1];
                        xm[4*c+0] = va[0] * lo0 + vb[1] * hi0;
                        xm[4*c+1] = va[1] * hi0 + vb[0] * lo0;
                        float lo1 = xm[4*c+2], hi1 = xm[4*c+3];
                        xm[4*c+2] = va[2] * lo1 + vb[3] * hi1;
                        xm[4*c+3] = va[3] * hi1 + vb[2] * lo1;
                    } else {               // pairs (0,2),(1,3)
                        float lo0 = xm[4*c+0], hi0 = xm[4*c+2];
                        xm[4*c+0] = va[0] * lo0 + vb[2] * hi0;
                        xm[4*c+2] = va[2] * hi0 + vb[0] * lo0;
                        float lo1 = xm[4*c+1], hi1 = xm[4*c+3];
                        xm[4*c+1] = va[1] * lo1 + vb[3] * hi1;
                        xm[4*c+3] = va[3] * hi1 + vb[1] * lo1;
                    }
                }
            }
        }
        // ---- stages 2,3 (s=4,8): pairs across quarters ----
        #pragma unroll
        for (int i = 2; i < 4; ++i) {
            const f4* A = reinterpret_cast<const f4*>(lp + (size_t)(2*i)   * 4096 + lane * 16);
            const f4* B = reinterpret_cast<const f4*>(lp + (size_t)(2*i+1) * 4096 + lane * 16);
            #pragma unroll
            for (int g = 0; g < 2; ++g) {
                const int q0 = (i == 2) ? 2 * g : g;       // s=4: (0,1),(2,3)
                const int q1 = (i == 2) ? q0 + 1 : q0 + 2; // s=8: (0,2),(1,3)
                f4 va0 = A[q0], va1 = A[q1], vb0 = B[q0], vb1 = B[q1];
                #pragma unroll
                for (int m = 0; m < 2; ++m) {
                    float* xm = x[m];
                    #pragma unroll
                    for (int e = 0; e < 4; ++e) {
                        float lo = xm[4*q0+e], hi = xm[4*q1+e];
                        xm[4*q0+e] = va0[e] * lo + vb1[e] * hi;
                        xm[4*q1+e] = va1[e] * hi + vb0[e] * lo;
                    }
                }
            }
        }
        // ---- stage 4 (d=1): DPP quad_perm exchange, coeff rows 8,9 ----
        {
            const f4* A = reinterpret_cast<const f4*>(lp + (size_t)8 * 4096 + lane * 16);
            const f4* B = reinterpret_cast<const f4*>(lp + (size_t)9 * 4096 + (lane ^ 1) * 16);
            #pragma unroll
            for (int c = 0; c < 4; ++c) {
                f4 va = A[c], vb = B[c];
                #pragma unroll
                for (int m = 0; m < 2; ++m) {
                    #pragma unroll
                    for (int e = 0; e < 4; ++e) {
                        float v = x[m][4*c+e];
                        x[m][4*c+e] = va[e] * v + vb[e] * dppx<0xB1>(v);
                    }
                }
            }
        }
        // ---- stages 5..9 (d=2,4,8,16,32): coeff from swizzled LDS ----
        #pragma unroll
        for (int i = 5; i < 10; ++i) {
            const int d = 1 << (i - 4);
            const float* arow = &cf[(size_t)(i - 5) * 2048];
            const float* brow = arow + 1024;
            #pragma unroll
            for (int c = 0; c < 4; ++c) {
                f4 va = *reinterpret_cast<const f4*>(&arow[swz(lane * 16 + 4 * c)]);
                f4 vb = *reinterpret_cast<const f4*>(&brow[swz((lane ^ d) * 16 + 4 * c)]);
                #pragma unroll
                for (int m = 0; m < 2; ++m) {
                    #pragma unroll
                    for (int e = 0; e < 4; ++e) {
                        float v = x[m][4*c+e];
                        float xp = (d == 2) ? dppx<0x4E>(v)
                                 : (d == 8) ? dppx<0x128>(v)
                                 :            __shfl_xor(v, d, 64);   // d = 4,16,32
                        x[m][4*c+e] = va[e] * v + vb[e] * xp;
                    }
                }
            }
        }
    };

    float* zz = &zb[(size_t)wave * 2048];      // 1024 f2 slots per wave (8 KB)
    const int km0 = (lane & 7) << 1;           // pair-preserving write swizzle
    const i4* srv = reinterpret_cast<const i4*>(src2);
    const f4* scv = reinterpret_cast<const f4*>(scale);

    auto emit = [&](float (&x)[2][16], int s0) {
        // interleaved z write: f2-slot pi = pz(c) for element c = lane*16+k
        #pragma unroll
        for (int k = 0; k < 16; k += 2) {
            int pi = lane * 16 + (k ^ km0);
            f4 v = { x[0][k], x[1][k], x[0][k+1], x[1][k+1] };
            *reinterpret_cast<f4*>(&zz[2 * pi]) = v;
        }
        // one b64 LDS read serves both samples; srv/scv pipelined 1 deep
        // ahead of the stores (wave-private region, no barrier needed).
        f4* o0 = reinterpret_cast<f4*>(out + (size_t)s0 * 4096);
        f4* o1 = reinterpret_cast<f4*>(out + (size_t)(s0 + 1) * 4096);
        i4 si = srv[lane];
        f4 sc = scv[lane];
        #pragma unroll
        for (int it = 0; it < 16; ++it) {
            i4 si_c = si;
            f4 sc_c = sc;
            if (it + 1 < 16) {                  // prefetch next iteration
                si = srv[(it + 1) * 64 + lane];
                sc = scv[(it + 1) * 64 + lane];
            }
            int j4 = it * 64 + lane;
            f2 vx = *reinterpret_cast<const f2*>(&zz[2 * si_c.x]);
            f2 vy = *reinterpret_cast<const f2*>(&zz[2 * si_c.y]);
            f2 vz = *reinterpret_cast<const f2*>(&zz[2 * si_c.z]);
            f2 vw = *reinterpret_cast<const f2*>(&zz[2 * si_c.w]);
            f4 r0 = { sc_c.x * vx.x, sc_c.y * vy.x, sc_c.z * vz.x, sc_c.w * vw.x };
            f4 r1 = { sc_c.x * vx.y, sc_c.y * vy.y, sc_c.z * vz.y, sc_c.w * vw.y };
            o0[j4] = r0;
            o1[j4] = r1;
        }
    };

    butterfly(xA);
    emit(xA, sBase);          // pair-0 stores drain while pair-1 computes
    butterfly(xB);
    emit(xB, sBase + 2);
}

extern "C" void kernel_launch(void* const* d_in, const int* in_sizes, int n_in,
                              void* d_out, int out_size, void* d_ws, size_t ws_size,
                              hipStream_t stream) {
    const float* inp  = (const float*)d_in[0];   // (8192, 1024) f32
    const float* lp   = (const float*)d_in[1];   // (24, 4096)  f32
    const int*   orow = (const int*)d_in[2];     // (4096,)     i32
    float* out = (float*)d_out;                  // (8192, 4096) f32

    float* scale = (float*)d_ws;                       // 4096 f32
    int*   src2  = (int*)((char*)d_ws + 4096 * 4);     // 4096 i32 (f2-slot idx)

    bfly_prep<<<16, 256, 0, stream>>>(lp, orow, scale, src2);
    bfly_main<<<512, 256, 0, stream>>>(inp, lp, scale, src2, out);
}

// Round 12
// 52.162 us; speedup vs baseline: 1.6650x; 1.6650x over previous
//
#include <hip/hip_runtime.h>

// OurButterflyLayer: N=4096, LOGN=12, IN=1024, OUT=4096, BATCH=8192
//
// out[s,j] = scale[j] * z_s[src[j]],  z_s = 10-stage butterfly (stages 0..9)
// on the 1024-float input row s; stages 10,11 + out-row gather fold into
// per-output (scale, src) pairs (elements >=1024 stay zero through stages
// 0..9 since all strides < 1024).
//
// Round-12: R10's verified butterfly + BLOCK-COOPERATIVE epilogue.
// R11 counters showed ~360 MB moved (2.2x ideal); biggest demand term was
// per-wave srv/scv reads (131 MB aggregate). Now: all 8 block samples' z
// live in the 40 KB cf-reuse region (4 pair-groups x 1024 f2 slots); after
// a barrier each wave gathers a 1024-COLUMN slice for ALL 8 samples ->
// srv/scv read once per block (demand 131 -> 32 MB), epilogue VMEM loads
// per wave 32 -> 8. LDS stays 40 KB -> 4 blocks/CU (the concurrency that
// sustained ~7 TB/s). Plain loads/stores (R7 fix).

typedef float f4 __attribute__((ext_vector_type(4)));
typedef float f2 __attribute__((ext_vector_type(2)));
typedef int   i4 __attribute__((ext_vector_type(4)));

__device__ __forceinline__ int swz(int e) {
    // XOR float-index bits [6:5] into [3:2]: keeps float4 alignment; makes
    // 64B-stride LDS coeff accesses bank-conflict-free.
    return e ^ (((e >> 5) & 3) << 2);
}

template<int CTRL>
__device__ __forceinline__ float dppx(float x) {
    int xi = __builtin_bit_cast(int, x);
    int r  = __builtin_amdgcn_update_dpp(xi, xi, CTRL, 0xF, 0xF, true);
    return __builtin_bit_cast(float, r);
}
// ctrl: quad_perm(1,0,3,2)=0xB1 (lane^1), quad_perm(2,3,0,1)=0x4E (lane^2),
// row_ror:8=0x128 (lane^8 within 16-lane row). Verified R4/R6/R7/R8/R10.

__global__ void __launch_bounds__(256) bfly_prep(
    const float* __restrict__ lp, const int* __restrict__ orow,
    float* __restrict__ scale, int* __restrict__ src2)
{
    int j = blockIdx.x * 256 + threadIdx.x;
    if (j >= 4096) return;
    int r = orow[j];
    int c = r & 1023;
    int u = r & 2047;
    const float* A10 = lp + 20 * 4096;
    const float* B10 = lp + 21 * 4096;
    const float* A11 = lp + 22 * 4096;
    const float* B11 = lp + 23 * 4096;
    float f11 = (r & 2048) ? B11[u] : A11[u];
    float f10 = (r & 1024) ? B10[c] : A10[c];
    scale[j] = f11 * f10;
    // f2-slot index with pair-preserving bank spread:
    // pz(c) = c ^ (((c>>4)&7)<<1)   (matches z-write slot algebra below)
    src2[j] = c ^ (((c >> 4) & 7) << 1);
}

__global__ void __launch_bounds__(256, 4) bfly_main(
    const float* __restrict__ inp, const float* __restrict__ lp,
    const float* __restrict__ scale, const int* __restrict__ src2,
    float* __restrict__ out)
{
    // 10 rows x 1024 floats: a,b for stages 5..9 (swizzled). Reused as the
    // block-wide paired-z buffer (4 pair-groups x 1024 f2 = 32 KB of 40 KB).
    __shared__ __align__(16) float cf[10 * 1024];
    const int t = threadIdx.x;
    const int wave = t >> 6, lane = t & 63;

    // cooperative coeff staging: lp rows 10..19, first 1024 floats of each
    #pragma unroll
    for (int q = 0; q < 10; ++q) {
        const f4 v = *reinterpret_cast<const f4*>(lp + (size_t)(10 + q) * 4096 + t * 4);
        *reinterpret_cast<f4*>(&cf[q * 1024 + swz(t * 4)]) = v;
    }

    const int sBlock = blockIdx.x * 8;             // block owns 8 samples
    const int sBase = sBlock + wave * 2;           // wave computes 2 of them
    float x[2][16];
    #pragma unroll
    for (int m = 0; m < 2; ++m) {
        const f4* p = reinterpret_cast<const f4*>(inp + (size_t)(sBase + m) * 1024 + lane * 16);
        #pragma unroll
        for (int c = 0; c < 4; ++c) {
            f4 v = p[c];
            x[m][4*c+0] = v.x; x[m][4*c+1] = v.y; x[m][4*c+2] = v.z; x[m][4*c+3] = v.w;
        }
    }

    __syncthreads();   // cf ready

    // ---- stages 0,1 (s=1,2): pairs within each f4 quarter ----
    #pragma unroll
    for (int i = 0; i < 2; ++i) {
        const f4* A = reinterpret_cast<const f4*>(lp + (size_t)(2*i)   * 4096 + lane * 16);
        const f4* B = reinterpret_cast<const f4*>(lp + (size_t)(2*i+1) * 4096 + lane * 16);
        #pragma unroll
        for (int c = 0; c < 4; ++c) {
            f4 va = A[c], vb = B[c];
            #pragma unroll
            for (int m = 0; m < 2; ++m) {
                float* xm = x[m];
                if (i == 0) {          // pairs (0,1),(2,3)
                    float lo0 = xm[4*c+0], hi0 = xm[4*c+1];
                    xm[4*c+0] = va[0] * lo0 + vb[1] * hi0;
                    xm[4*c+1] = va[1] * hi0 + vb[0] * lo0;
                    float lo1 = xm[4*c+2], hi1 = xm[4*c+3];
                    xm[4*c+2] = va[2] * lo1 + vb[3] * hi1;
                    xm[4*c+3] = va[3] * hi1 + vb[2] * lo1;
                } else {               // pairs (0,2),(1,3)
                    float lo0 = xm[4*c+0], hi0 = xm[4*c+2];
                    xm[4*c+0] = va[0] * lo0 + vb[2] * hi0;
                    xm[4*c+2] = va[2] * hi0 + vb[0] * lo0;
                    float lo1 = xm[4*c+1], hi1 = xm[4*c+3];
                    xm[4*c+1] = va[1] * lo1 + vb[3] * hi1;
                    xm[4*c+3] = va[3] * hi1 + vb[1] * lo1;
                }
            }
        }
    }

    // ---- stages 2,3 (s=4,8): pairs across quarters ----
    #pragma unroll
    for (int i = 2; i < 4; ++i) {
        const f4* A = reinterpret_cast<const f4*>(lp + (size_t)(2*i)   * 4096 + lane * 16);
        const f4* B = reinterpret_cast<const f4*>(lp + (size_t)(2*i+1) * 4096 + lane * 16);
        #pragma unroll
        for (int g = 0; g < 2; ++g) {
            const int q0 = (i == 2) ? 2 * g : g;       // s=4: (0,1),(2,3)
            const int q1 = (i == 2) ? q0 + 1 : q0 + 2; // s=8: (0,2),(1,3)
            f4 va0 = A[q0], va1 = A[q1], vb0 = B[q0], vb1 = B[q1];
            #pragma unroll
            for (int m = 0; m < 2; ++m) {
                float* xm = x[m];
                #pragma unroll
                for (int e = 0; e < 4; ++e) {
                    float lo = xm[4*q0+e], hi = xm[4*q1+e];
                    xm[4*q0+e] = va0[e] * lo + vb1[e] * hi;
                    xm[4*q1+e] = va1[e] * hi + vb0[e] * lo;
                }
            }
        }
    }

    // ---- stage 4 (d=1): DPP quad_perm exchange, coeff rows 8,9 ----
    {
        const f4* A = reinterpret_cast<const f4*>(lp + (size_t)8 * 4096 + lane * 16);
        const f4* B = reinterpret_cast<const f4*>(lp + (size_t)9 * 4096 + (lane ^ 1) * 16);
        #pragma unroll
        for (int c = 0; c < 4; ++c) {
            f4 va = A[c], vb = B[c];
            #pragma unroll
            for (int m = 0; m < 2; ++m) {
                #pragma unroll
                for (int e = 0; e < 4; ++e) {
                    float v = x[m][4*c+e];
                    x[m][4*c+e] = va[e] * v + vb[e] * dppx<0xB1>(v);
                }
            }
        }
    }

    // ---- stages 5..9 (d=2,4,8,16,32): coeff from swizzled LDS ----
    #pragma unroll
    for (int i = 5; i < 10; ++i) {
        const int d = 1 << (i - 4);
        const float* arow = &cf[(size_t)(i - 5) * 2048];
        const float* brow = arow + 1024;
        #pragma unroll
        for (int c = 0; c < 4; ++c) {
            f4 va = *reinterpret_cast<const f4*>(&arow[swz(lane * 16 + 4 * c)]);
            f4 vb = *reinterpret_cast<const f4*>(&brow[swz((lane ^ d) * 16 + 4 * c)]);
            #pragma unroll
            for (int m = 0; m < 2; ++m) {
                #pragma unroll
                for (int e = 0; e < 4; ++e) {
                    float v = x[m][4*c+e];
                    float xp = (d == 2) ? dppx<0x4E>(v)
                             : (d == 8) ? dppx<0x128>(v)
                             :            __shfl_xor(v, d, 64);   // d = 4,16,32
                    x[m][4*c+e] = va[e] * v + vb[e] * xp;
                }
            }
        }
    }

    __syncthreads();   // all coeff reads done; reuse cf as block-wide z

    // z write (R7-verified slot algebra): pair-group `wave`, f2-slot
    // pi = pz(c) = c ^ (((c>>4)&7)<<1) for element c = lane*16+k.
    {
        float* zz = &cf[(size_t)wave * 2048];
        const int km0 = (lane & 7) << 1;
        #pragma unroll
        for (int k = 0; k < 16; k += 2) {
            int pi = lane * 16 + (k ^ km0);
            f4 v = { x[0][k], x[1][k], x[0][k+1], x[1][k+1] };
            *reinterpret_cast<f4*>(&zz[2 * pi]) = v;
        }
    }

    __syncthreads();   // z visible block-wide

    // block-cooperative epilogue: wave w gathers columns [w*1024, w*1024+1024)
    // for ALL 8 samples -> srv/scv read ONCE per block.
    const i4* srv = reinterpret_cast<const i4*>(src2);
    const f4* scv = reinterpret_cast<const f4*>(scale);
    float* obase = out + (size_t)sBlock * 4096;

    #pragma unroll
    for (int it = 0; it < 4; ++it) {
        int j4 = wave * 256 + it * 64 + lane;   // f4-column index in [0,1024)
        i4 si = srv[j4];
        f4 sc = scv[j4];
        #pragma unroll
        for (int p = 0; p < 4; ++p) {
            const float* zp = &cf[(size_t)p * 2048];
            f2 vx = *reinterpret_cast<const f2*>(&zp[2 * si.x]);
            f2 vy = *reinterpret_cast<const f2*>(&zp[2 * si.y]);
            f2 vz = *reinterpret_cast<const f2*>(&zp[2 * si.z]);
            f2 vw = *reinterpret_cast<const f2*>(&zp[2 * si.w]);
            f4 r0 = { sc.x * vx.x, sc.y * vy.x, sc.z * vz.x, sc.w * vw.x };
            f4 r1 = { sc.x * vx.y, sc.y * vy.y, sc.z * vz.y, sc.w * vw.y };
            reinterpret_cast<f4*>(obase + (size_t)(2 * p)     * 4096)[j4] = r0;
            reinterpret_cast<f4*>(obase + (size_t)(2 * p + 1) * 4096)[j4] = r1;
        }
    }
}

extern "C" void kernel_launch(void* const* d_in, const int* in_sizes, int n_in,
                              void* d_out, int out_size, void* d_ws, size_t ws_size,
                              hipStream_t stream) {
    const float* inp  = (const float*)d_in[0];   // (8192, 1024) f32
    const float* lp   = (const float*)d_in[1];   // (24, 4096)  f32
    const int*   orow = (const int*)d_in[2];     // (4096,)     i32
    float* out = (float*)d_out;                  // (8192, 4096) f32

    float* scale = (float*)d_ws;                       // 4096 f32
    int*   src2  = (int*)((char*)d_ws + 4096 * 4);     // 4096 i32 (f2-slot idx)

    bfly_prep<<<16, 256, 0, stream>>>(lp, orow, scale, src2);
    bfly_main<<<1024, 256, 0, stream>>>(inp, lp, scale, src2, out);
}

// Round 13
// 42.475 us; speedup vs baseline: 2.0448x; 1.2281x over previous
//
#include <hip/hip_runtime.h>

// OurButterflyLayer: N=4096, LOGN=12, IN=1024, OUT=4096, BATCH=8192
//
// out[s,j] = scale[j] * z_s[src[j]],  z_s = 10-stage butterfly (stages 0..9)
// on the 1024-float input row s; stages 10,11 + out-row gather fold into
// per-output (scale, src) pairs (elements >=1024 stay zero through stages
// 0..9 since all strides < 1024).
//
// Round-13: 512-thr blocks (8 waves), ALL 20 coeff rows in 80 KB swizzled
// LDS (no per-stage L2 latency chains), 64 KB wave-private paired-z scratch
// (144 KB total -> 1 block/CU), grid 512 -> 2 sequential blocks per CU so
// block 2's staging/input overlaps block 1's store tail. ONE barrier total.
// Butterfly / exchanges / z-slot algebra / epilogue = R7/R10 verified code.
// Plain loads/stores (R7 fix), 1-deep pipelined epilogue loads.

typedef float f4 __attribute__((ext_vector_type(4)));
typedef float f2 __attribute__((ext_vector_type(2)));
typedef int   i4 __attribute__((ext_vector_type(4)));

__device__ __forceinline__ int swz(int e) {
    // XOR float-index bits [6:5] into [3:2]: keeps float4 alignment; makes
    // 64B-stride LDS coeff accesses bank-conflict-free.
    return e ^ (((e >> 5) & 3) << 2);
}

template<int CTRL>
__device__ __forceinline__ float dppx(float x) {
    int xi = __builtin_bit_cast(int, x);
    int r  = __builtin_amdgcn_update_dpp(xi, xi, CTRL, 0xF, 0xF, true);
    return __builtin_bit_cast(float, r);
}
// ctrl: quad_perm(1,0,3,2)=0xB1 (lane^1), quad_perm(2,3,0,1)=0x4E (lane^2),
// row_ror:8=0x128 (lane^8 within 16-lane row). Verified R4/R6/R7/R8/R10.

__global__ void __launch_bounds__(256) bfly_prep(
    const float* __restrict__ lp, const int* __restrict__ orow,
    float* __restrict__ scale, int* __restrict__ src2)
{
    int j = blockIdx.x * 256 + threadIdx.x;
    if (j >= 4096) return;
    int r = orow[j];
    int c = r & 1023;
    int u = r & 2047;
    const float* A10 = lp + 20 * 4096;
    const float* B10 = lp + 21 * 4096;
    const float* A11 = lp + 22 * 4096;
    const float* B11 = lp + 23 * 4096;
    float f11 = (r & 2048) ? B11[u] : A11[u];
    float f10 = (r & 1024) ? B10[c] : A10[c];
    scale[j] = f11 * f10;
    // f2-slot index with pair-preserving bank spread:
    // pz(c) = c ^ (((c>>4)&7)<<1)   (matches z-write slot algebra below)
    src2[j] = c ^ (((c >> 4) & 7) << 1);
}

__global__ void __launch_bounds__(512, 2) bfly_main(
    const float* __restrict__ inp, const float* __restrict__ lp,
    const float* __restrict__ scale, const int* __restrict__ src2,
    float* __restrict__ out)
{
    // [0, 20480): 20 coeff rows (stages 0..9 a,b), swizzled. persistent.
    // [20480, 36864): 8 waves x 1024 paired-f2 z slots (8 KB each).
    __shared__ __align__(16) float cf[20 * 1024 + 8 * 2048];
    const int t = threadIdx.x;
    const int wave = t >> 6, lane = t & 63;

    // cooperative coeff staging: rows 0..19 of lp (first 1024 floats each);
    // 512 threads stage two rows per step.
    #pragma unroll
    for (int step = 0; step < 10; ++step) {
        const int q = 2 * step + (t >> 8);
        const int e = (t & 255) * 4;
        const f4 v = *reinterpret_cast<const f4*>(lp + (size_t)q * 4096 + e);
        *reinterpret_cast<f4*>(&cf[q * 1024 + swz(e)]) = v;
    }

    const int sBase = blockIdx.x * 16 + wave * 2;   // 2 samples per wave
    float x[2][16];
    #pragma unroll
    for (int m = 0; m < 2; ++m) {
        const f4* p = reinterpret_cast<const f4*>(inp + (size_t)(sBase + m) * 1024 + lane * 16);
        #pragma unroll
        for (int c = 0; c < 4; ++c) {
            f4 v = p[c];
            x[m][4*c+0] = v.x; x[m][4*c+1] = v.y; x[m][4*c+2] = v.z; x[m][4*c+3] = v.w;
        }
    }

    __syncthreads();   // cf ready — the only barrier in the kernel

    // ---- stages 0,1 (s=1,2): pairs within each f4 quarter; coeff from LDS ----
    #pragma unroll
    for (int i = 0; i < 2; ++i) {
        const float* arow = &cf[(size_t)(2*i)     * 1024];
        const float* brow = &cf[(size_t)(2*i + 1) * 1024];
        #pragma unroll
        for (int c = 0; c < 4; ++c) {
            f4 va = *reinterpret_cast<const f4*>(&arow[swz(lane * 16 + 4 * c)]);
            f4 vb = *reinterpret_cast<const f4*>(&brow[swz(lane * 16 + 4 * c)]);
            #pragma unroll
            for (int m = 0; m < 2; ++m) {
                float* xm = x[m];
                if (i == 0) {          // pairs (0,1),(2,3)
                    float lo0 = xm[4*c+0], hi0 = xm[4*c+1];
                    xm[4*c+0] = va[0] * lo0 + vb[1] * hi0;
                    xm[4*c+1] = va[1] * hi0 + vb[0] * lo0;
                    float lo1 = xm[4*c+2], hi1 = xm[4*c+3];
                    xm[4*c+2] = va[2] * lo1 + vb[3] * hi1;
                    xm[4*c+3] = va[3] * hi1 + vb[2] * lo1;
                } else {               // pairs (0,2),(1,3)
                    float lo0 = xm[4*c+0], hi0 = xm[4*c+2];
                    xm[4*c+0] = va[0] * lo0 + vb[2] * hi0;
                    xm[4*c+2] = va[2] * hi0 + vb[0] * lo0;
                    float lo1 = xm[4*c+1], hi1 = xm[4*c+3];
                    xm[4*c+1] = va[1] * lo1 + vb[3] * hi1;
                    xm[4*c+3] = va[3] * hi1 + vb[1] * lo1;
                }
            }
        }
    }

    // ---- stages 2,3 (s=4,8): pairs across quarters; coeff from LDS ----
    #pragma unroll
    for (int i = 2; i < 4; ++i) {
        const float* arow = &cf[(size_t)(2*i)     * 1024];
        const float* brow = &cf[(size_t)(2*i + 1) * 1024];
        #pragma unroll
        for (int g = 0; g < 2; ++g) {
            const int q0 = (i == 2) ? 2 * g : g;       // s=4: (0,1),(2,3)
            const int q1 = (i == 2) ? q0 + 1 : q0 + 2; // s=8: (0,2),(1,3)
            f4 va0 = *reinterpret_cast<const f4*>(&arow[swz(lane * 16 + 4 * q0)]);
            f4 va1 = *reinterpret_cast<const f4*>(&arow[swz(lane * 16 + 4 * q1)]);
            f4 vb0 = *reinterpret_cast<const f4*>(&brow[swz(lane * 16 + 4 * q0)]);
            f4 vb1 = *reinterpret_cast<const f4*>(&brow[swz(lane * 16 + 4 * q1)]);
            #pragma unroll
            for (int m = 0; m < 2; ++m) {
                float* xm = x[m];
                #pragma unroll
                for (int e = 0; e < 4; ++e) {
                    float lo = xm[4*q0+e], hi = xm[4*q1+e];
                    xm[4*q0+e] = va0[e] * lo + vb1[e] * hi;
                    xm[4*q1+e] = va1[e] * hi + vb0[e] * lo;
                }
            }
        }
    }

    // ---- stage 4 (d=1): DPP quad_perm exchange; coeff rows 8,9 from LDS ----
    {
        const float* arow = &cf[(size_t)8 * 1024];
        const float* brow = &cf[(size_t)9 * 1024];
        #pragma unroll
        for (int c = 0; c < 4; ++c) {
            f4 va = *reinterpret_cast<const f4*>(&arow[swz(lane * 16 + 4 * c)]);
            f4 vb = *reinterpret_cast<const f4*>(&brow[swz((lane ^ 1) * 16 + 4 * c)]);
            #pragma unroll
            for (int m = 0; m < 2; ++m) {
                #pragma unroll
                for (int e = 0; e < 4; ++e) {
                    float v = x[m][4*c+e];
                    x[m][4*c+e] = va[e] * v + vb[e] * dppx<0xB1>(v);
                }
            }
        }
    }

    // ---- stages 5..9 (d=2,4,8,16,32): coeff rows 10..19 from LDS ----
    #pragma unroll
    for (int i = 5; i < 10; ++i) {
        const int d = 1 << (i - 4);
        const float* arow = &cf[(size_t)(2*i)     * 1024];
        const float* brow = &cf[(size_t)(2*i + 1) * 1024];
        #pragma unroll
        for (int c = 0; c < 4; ++c) {
            f4 va = *reinterpret_cast<const f4*>(&arow[swz(lane * 16 + 4 * c)]);
            f4 vb = *reinterpret_cast<const f4*>(&brow[swz((lane ^ d) * 16 + 4 * c)]);
            #pragma unroll
            for (int m = 0; m < 2; ++m) {
                #pragma unroll
                for (int e = 0; e < 4; ++e) {
                    float v = x[m][4*c+e];
                    float xp = (d == 2) ? dppx<0x4E>(v)
                             : (d == 8) ? dppx<0x128>(v)
                             :            __shfl_xor(v, d, 64);   // d = 4,16,32
                    x[m][4*c+e] = va[e] * v + vb[e] * xp;
                }
            }
        }
    }

    // z write (R7-verified slot algebra) into this wave's private region.
    float* zz = &cf[20 * 1024 + (size_t)wave * 2048];  // 1024 f2 slots
    const int km0 = (lane & 7) << 1;                   // pair-preserving swizzle
    #pragma unroll
    for (int k = 0; k < 16; k += 2) {
        int pi = lane * 16 + (k ^ km0);
        f4 v = { x[0][k], x[1][k], x[0][k+1], x[1][k+1] };
        *reinterpret_cast<f4*>(&zz[2 * pi]) = v;
    }

    // epilogue (R7-verified): one b64 LDS read serves both samples; srv/scv
    // pipelined 1 deep ahead of the stores. Wave-private region, no barrier.
    const i4* srv = reinterpret_cast<const i4*>(src2);
    const f4* scv = reinterpret_cast<const f4*>(scale);
    f4* o0 = reinterpret_cast<f4*>(out + (size_t)sBase * 4096);
    f4* o1 = reinterpret_cast<f4*>(out + (size_t)(sBase + 1) * 4096);

    i4 si = srv[lane];
    f4 sc = scv[lane];
    #pragma unroll
    for (int it = 0; it < 16; ++it) {
        i4 si_c = si;
        f4 sc_c = sc;
        if (it + 1 < 16) {                      // prefetch next iteration
            si = srv[(it + 1) * 64 + lane];
            sc = scv[(it + 1) * 64 + lane];
        }
        int j4 = it * 64 + lane;
        f2 vx = *reinterpret_cast<const f2*>(&zz[2 * si_c.x]);
        f2 vy = *reinterpret_cast<const f2*>(&zz[2 * si_c.y]);
        f2 vz = *reinterpret_cast<const f2*>(&zz[2 * si_c.z]);
        f2 vw = *reinterpret_cast<const f2*>(&zz[2 * si_c.w]);
        f4 r0 = { sc_c.x * vx.x, sc_c.y * vy.x, sc_c.z * vz.x, sc_c.w * vw.x };
        f4 r1 = { sc_c.x * vx.y, sc_c.y * vy.y, sc_c.z * vz.y, sc_c.w * vw.y };
        o0[j4] = r0;
        o1[j4] = r1;
    }
}

extern "C" void kernel_launch(void* const* d_in, const int* in_sizes, int n_in,
                              void* d_out, int out_size, void* d_ws, size_t ws_size,
                              hipStream_t stream) {
    const float* inp  = (const float*)d_in[0];   // (8192, 1024) f32
    const float* lp   = (const float*)d_in[1];   // (24, 4096)  f32
    const int*   orow = (const int*)d_in[2];     // (4096,)     i32
    float* out = (float*)d_out;                  // (8192, 4096) f32

    float* scale = (float*)d_ws;                       // 4096 f32
    int*   src2  = (int*)((char*)d_ws + 4096 * 4);     // 4096 i32 (f2-slot idx)

    bfly_prep<<<16, 256, 0, stream>>>(lp, orow, scale, src2);
    bfly_main<<<512, 512, 0, stream>>>(inp, lp, scale, src2, out);
}